// Round 1
// 177.183 us; speedup vs baseline: 1.0047x; 1.0047x over previous
//
#include <hip/hip_runtime.h>

typedef __bf16 bf16;
typedef __bf16 bf16x4v __attribute__((ext_vector_type(4)));
typedef __bf16 bf16x8 __attribute__((ext_vector_type(8)));
typedef float f32x4 __attribute__((ext_vector_type(4)));
typedef short s16x4 __attribute__((ext_vector_type(4)));

#define MFMA_X32(A, B, C) __builtin_amdgcn_mfma_f32_16x16x32_bf16(A, B, C, 0, 0, 0)

#if __has_builtin(__builtin_amdgcn_mfma_f32_16x16x16_bf16)
static __device__ __forceinline__ f32x4 mfma_x16(bf16x4v a, bf16x4v b, f32x4 c) {
  return __builtin_amdgcn_mfma_f32_16x16x16_bf16(a, b, c, 0, 0, 0);
}
#else
static __device__ __forceinline__ f32x4 mfma_x16(bf16x4v a, bf16x4v b, f32x4 c) {
  return __builtin_amdgcn_mfma_f32_16x16x16bf16_1k(
      __builtin_bit_cast(s16x4, a), __builtin_bit_cast(s16x4, b), c, 0, 0, 0);
}
#endif

static __device__ __forceinline__ float fast_exp2(float x) {
  float r;
  asm volatile("v_exp_f32 %0, %1\n\ts_nop 0" : "=v"(r) : "v"(x));
  return r;
}

static __device__ __forceinline__ void gll16(const void* g, void* l) {
  __builtin_amdgcn_global_load_lds(
      (const __attribute__((address_space(1))) void*)g,
      (__attribute__((address_space(3))) void*)l, 16, 0, 0);
}

// ---- workspace byte offsets (UNCHANGED — flash layout contracts intact) ----
#define WT_OFF 0              // Wt bf16 [3][256 n][256 k]          (384 KB)
#define Q_OFF 393216          // Q' bf16 [16384][256] (pre-scaled)   (8 MB)
#define K_OFF 8781824         // Kc bf16 chunk-permuted (see below)  (8 MB)
#define V_OFF 17170432        // Vc bf16 chunk-permuted (see below)  (8 MB)
// Kc: per (b, 16-key chunk) 8KB block; element (key s, dim n) at
//   (n>>5)*512 + ((n>>3)&3)*128 + (s&15)*8 + (n&7)
// Vc: per (b, 16-key chunk) 8KB block; element (key s, dim d=n) at
//   (n>>4)*256 + ((s&15)>>2)*64 + (n&15)*4 + (s&3)
// NOTE: for a fixed 128-col half ch, a chunk's half is CONTIGUOUS:
//   K: [ch*2048, ch*2048+2048) elems;  V: [ch*2048, ch*2048+2048) elems.
// proj_qkv exploits this: scatter into LDS in-permutation, then fully
// coalesced 32B/thread global writes (old version: 96 scattered 2B
// stores per thread — the hypothesized 10x latency hole).

// ---------------------------------------------------------------------------
// Kernel 1: W [k][n] fp32 -> Wt bf16 [p][n][k]   (unchanged)
// ---------------------------------------------------------------------------
__global__ __launch_bounds__(256) void prep_wt(const float* __restrict__ Wq,
                                               const float* __restrict__ Wk,
                                               const float* __restrict__ Wv,
                                               bf16* __restrict__ Wt) {
  const int idx = blockIdx.x * 256 + threadIdx.x;
  const int p = idx >> 16;
  const int rem = idx & 65535;  // k*256 + n
  const int k = rem >> 8, n = rem & 255;
  const float* W = (p == 0) ? Wq : ((p == 1) ? Wk : Wv);
  Wt[p * 65536 + n * 256 + k] = (bf16)W[rem];
}

// ---------------------------------------------------------------------------
// Kernel 2 (REWRITTEN): weight-stationary QKV projection.
// Block = (p, 128-col half); B-frags persist in 64 VGPR/wave (Wt staged ZERO
// times per tile — was 32KB/quarter). Loop 4 x 32-row x-tiles:
//   x fp32 -> bf16 into XOR-swizzled LDS (2-way banks on A-frag reads),
//   double-buffered, loads issued early (T14).
//   acc -> LDS out-tile in the flash permutation (cheap ds_write_b16),
//   then coalesced dwordx4 global writes.
// 8 barriers/block total (was 24); zero scattered global stores (was 96/thr).
// Grid 768 = 3 blocks/CU; LDS 40KB; ~140 VGPR.
// ---------------------------------------------------------------------------
__global__ __launch_bounds__(256, 3) void proj_qkv(const float* __restrict__ x,
                                                   const float* __restrict__ bq,
                                                   const float* __restrict__ bk,
                                                   const float* __restrict__ bv,
                                                   char* __restrict__ ws0) {
  __shared__ __align__(16) char smem[40960];  // 2 x 16KB swizzled x-tile + 8KB out
  const bf16* Wt = (const bf16*)(ws0 + WT_OFF);
  bf16* Qo = (bf16*)(ws0 + Q_OFF);
  bf16* Ko = (bf16*)(ws0 + K_OFF);
  bf16* Vc = (bf16*)(ws0 + V_OFF);
  const int t = threadIdx.x;
  const int lane = t & 63, w = t >> 6, l16 = lane & 15, quad = lane >> 4;
  const int fam = blockIdx.x % 6;    // consecutive blocks: same rows, all 6
  const int rgroup = blockIdx.x / 6; // families -> x tiles L2/L3-hot across XCDs
  const int p = fam >> 1, ch = fam & 1;
  const float* bias = (p == 0) ? bq : ((p == 1) ? bk : bv);
  const float sc = (p == 0) ? 0.09016844005556021f : 1.0f;  // log2e/16

  // ---- persistent B-frags: wave owns 32 cols (2 x 16), full K=256 ----
  const int nl = w * 32 + l16;  // block-local col, nt adds +16
  bf16x8 bfr[2][8];
#pragma unroll
  for (int nt = 0; nt < 2; ++nt)
#pragma unroll
    for (int kt = 0; kt < 8; ++kt)
      bfr[nt][kt] = *(const bf16x8*)&Wt[p * 65536 + (ch * 128 + nl + nt * 16) * 256 +
                                        kt * 32 + quad * 8];
  float bias2[2];
#pragma unroll
  for (int nt = 0; nt < 2; ++nt) bias2[nt] = bias[ch * 128 + nl + nt * 16];

  const int row0 = rgroup * 128;  // global first row of this block
  char* outL = smem + 32768;

  float4 xr[4][2];  // in-flight x tile (32 rows x 256 fp32 / 256 thr = 128B/thr)
#define STAGE_LOAD(tile)                                                        \
  {                                                                             \
    const float* xp = x + (row0 + (tile) * 32) * 256;                           \
    _Pragma("unroll") for (int i = 0; i < 4; ++i) {                             \
      const int u2 = i * 256 + t, row = u2 >> 5, col8 = (u2 & 31) * 8;          \
      xr[i][0] = *(const float4*)&xp[row * 256 + col8];                         \
      xr[i][1] = *(const float4*)&xp[row * 256 + col8 + 4];                     \
    }                                                                           \
  }
#define STAGE_WRITE(buf)                                                        \
  {                                                                             \
    _Pragma("unroll") for (int i = 0; i < 4; ++i) {                             \
      const int u2 = i * 256 + t, row = u2 >> 5, col8 = (u2 & 31) * 8;          \
      const float* f0 = (const float*)&xr[i][0];                                \
      const float* f1 = (const float*)&xr[i][1];                                \
      bf16x8 h;                                                                 \
      _Pragma("unroll") for (int j = 0; j < 4; ++j) {                           \
        h[j] = (bf16)f0[j];                                                     \
        h[4 + j] = (bf16)f1[j];                                                 \
      }                                                                         \
      *(bf16x8*)&smem[(buf) * 16384 + row * 512 +                               \
                      ((col8 * 2) ^ ((row & 7) << 4))] = h;                     \
    }                                                                           \
  }

  STAGE_LOAD(0);
  STAGE_WRITE(0);
  __syncthreads();

  int cur = 0;
  for (int tt = 0; tt < 4; ++tt) {
    if (tt < 3) STAGE_LOAD(tt + 1);  // issue early; consumed after next barrier

    // ---- 32 MFMAs from swizzled LDS A-frags + register B-frags ----
    f32x4 acc[2][2];
#pragma unroll
    for (int rs = 0; rs < 2; ++rs)
#pragma unroll
      for (int nt = 0; nt < 2; ++nt) acc[rs][nt] = f32x4{0.f, 0.f, 0.f, 0.f};
    const char* xb = smem + cur * 16384;
#pragma unroll
    for (int rs = 0; rs < 2; ++rs) {
      const int row = rs * 16 + l16;
#pragma unroll
      for (int kt = 0; kt < 8; ++kt) {
        const bf16x8 a = *(const bf16x8*)(xb + row * 512 +
                                          ((kt * 64 + quad * 16) ^ ((l16 & 7) << 4)));
        acc[rs][0] = MFMA_X32(a, bfr[0][kt], acc[rs][0]);
        acc[rs][1] = MFMA_X32(a, bfr[1][kt], acc[rs][1]);
      }
    }
    __syncthreads();  // prev tile's coop-write reads of outL complete

    // ---- scatter acc into outL in the flash permutation ----
#pragma unroll
    for (int rs = 0; rs < 2; ++rs)
#pragma unroll
      for (int nt = 0; nt < 2; ++nt)
#pragma unroll
        for (int r = 0; r < 4; ++r) {
          const int sl = rs * 16 + quad * 4 + r;  // C/D: row = quad*4+r
          const int nn = nl + nt * 16;            // block-local col 0..127
          const bf16 hv = (bf16)((acc[rs][nt][r] + bias2[nt]) * sc);
          int pos;
          if (p == 0)
            pos = sl * 128 + nn;
          else if (p == 1)
            pos = (sl >> 4) * 2048 + (nn >> 5) * 512 + ((nn >> 3) & 3) * 128 +
                  (sl & 15) * 8 + (nn & 7);
          else
            pos = (sl >> 4) * 2048 + (nn >> 4) * 256 + ((sl & 15) >> 2) * 64 +
                  (nn & 15) * 4 + (sl & 3);
          *(bf16*)(outL + pos * 2) = hv;
        }
    if (tt < 3) STAGE_WRITE(cur ^ 1);
    __syncthreads();  // scatter + next x-tile visible to all waves

    // ---- coalesced 32B/thread write of the 8KB out tile ----
    const int rowg = row0 + tt * 32;
    if (p == 0) {
      const int row = t >> 3, cb = (t & 7) * 32;
      const float4 v0 = *(const float4*)(outL + row * 256 + cb);
      const float4 v1 = *(const float4*)(outL + row * 256 + cb + 16);
      char* dst = (char*)Qo + (rowg + row) * 512 + ch * 256 + cb;
      *(float4*)dst = v0;
      *(float4*)(dst + 16) = v1;
    } else {
      const int b2 = rowg >> 11, s0 = rowg & 2047;
      bf16* O = (p == 1) ? Ko : Vc;
      char* dst = (char*)O + b2 * 1048576 + ((s0 >> 4) + (t >> 7)) * 8192 +
                  ch * 4096 + (t & 127) * 32;
      const float4 v0 = *(const float4*)(outL + t * 32);
      const float4 v1 = *(const float4*)(outL + t * 32 + 16);
      *(float4*)dst = v0;
      *(float4*)(dst + 16) = v1;
    }
    cur ^= 1;
  }
#undef STAGE_LOAD
#undef STAGE_WRITE
}

// ---------------------------------------------------------------------------
// Kernel 3: flash attention (UNCHANGED — control for this round).
// ---------------------------------------------------------------------------
#define BUF_SZ 65536   // half: 4 kq * (K 8KB + V 8KB), no pads
#define SLOT_SZ 16640  // merge slot: 16 rows * 260 floats

__global__ __launch_bounds__(512, 2) void flash_attn(const char* __restrict__ ws0,
                                                     float* __restrict__ out) {
  __shared__ __align__(1024) char smem[135168];  // 2*BUF_SZ + merge scratch
  const bf16* Qp = (const bf16*)(ws0 + Q_OFF);
  const int t = threadIdx.x;
  const int lane = t & 63, w = t >> 6;
  const int l16 = lane & 15, quad = lane >> 4;
  const int qs = w & 1, kq = w >> 1;
  const int b = blockIdx.x & 7;  // batch == XCD round-robin: K/V L2-resident
  const int qt = blockIdx.x >> 3;
  const int qrow0 = b * 2048 + qt * 64 + qs * 32;

  bf16x8 qf[2][8];
#pragma unroll
  for (int qsub = 0; qsub < 2; ++qsub)
#pragma unroll
    for (int kt = 0; kt < 8; ++kt)
      qf[qsub][kt] =
          *(const bf16x8*)&Qp[(qrow0 + qsub * 16 + l16) * 256 + kt * 32 + quad * 8];

  f32x4 o[2][16];
#pragma unroll
  for (int qsub = 0; qsub < 2; ++qsub)
#pragma unroll
    for (int dt = 0; dt < 16; ++dt) o[qsub][dt] = f32x4{0.f, 0.f, 0.f, 0.f};
  float m_[2] = {-1e30f, -1e30f}, l_[2] = {0.f, 0.f};

  // staging assignment: 8 GLL units (1 KB each) per wave per iter
  unsigned goff[8], loff[8];
#pragma unroll
  for (int i = 0; i < 8; ++i) {
    const int u = w * 8 + i;
    const int kq2 = (u & 31) >> 3, e = u & 7;
    goff[i] = (u < 32 ? (unsigned)K_OFF : (unsigned)V_OFF) + b * 1048576u +
              kq2 * 262144u + e * 1024u + lane * 16u;
    loff[i] = kq2 * 16384u + (u < 32 ? 0u : 8192u) + e * 1024u;
  }
#pragma unroll
  for (int i = 0; i < 8; ++i) gll16(ws0 + goff[i], smem + loff[i]);

  for (int it = 0; it < 32; ++it) {
    __syncthreads();  // chunk `it` resident; prev-iter reads of `nxt` done
    const unsigned cur = (unsigned)(it & 1) * BUF_SZ;
    if (it + 1 < 32) {
      const unsigned nxt = (unsigned)((it + 1) & 1) * BUF_SZ;
      const unsigned gadd = (unsigned)(it + 1) * 8192u;
#pragma unroll
      for (int i = 0; i < 8; ++i) gll16(ws0 + goff[i] + gadd, smem + nxt + loff[i]);
    }

    // ---- Sᵀ = K_chunk · Q'ᵀ (16 keys x 32 q); K reads LINEAR b128 ----
    const char* kb = smem + cur + kq * 16384 + lane * 16;
    f32x4 s0 = f32x4{0.f, 0.f, 0.f, 0.f}, s1 = s0;
#pragma unroll
    for (int kt = 0; kt < 8; ++kt) {
      const bf16x8 kf = *(const bf16x8*)(kb + kt * 1024);
      s0 = MFMA_X32(kf, qf[0][kt], s0);
      s1 = MFMA_X32(kf, qf[1][kt], s1);
    }

    // ---- online softmax (log2 domain; q = l16, key = quad*4+r) ----
    bf16x4v pa[2];
#pragma unroll
    for (int qsub = 0; qsub < 2; ++qsub) {
      const f32x4 s = qsub ? s1 : s0;
      float cm = fmaxf(fmaxf(s[0], s[1]), fmaxf(s[2], s[3]));
      cm = fmaxf(cm, __shfl_xor(cm, 16));
      cm = fmaxf(cm, __shfl_xor(cm, 32));
      const float mold = m_[qsub];
      const float mnew = fmaxf(mold, cm);
      bf16x4v pp;
      float ps = 0.f;
#pragma unroll
      for (int r = 0; r < 4; ++r) {
        const float e = fast_exp2(s[r] - mnew);
        const bf16 pb = (bf16)e;
        pp[r] = pb;
        ps += (float)pb;  // sum ROUNDED p for O/l consistency
      }
      ps += __shfl_xor(ps, 16);
      ps += __shfl_xor(ps, 32);
      if (__any(mnew > mold)) {
        const float al = fast_exp2(mold - mnew);
        m_[qsub] = mnew;
        l_[qsub] = l_[qsub] * al + ps;
        float ar[4];
#pragma unroll
        for (int r = 0; r < 4; ++r)
          ar[r] = __shfl(al, (quad << 4) + (quad << 2) + r);
#pragma unroll
        for (int dt = 0; dt < 16; ++dt)
#pragma unroll
          for (int r = 0; r < 4; ++r) o[qsub][dt][r] *= ar[r];
      } else {
        l_[qsub] += ps;
      }
      pa[qsub] = pp;  // Sᵀ C-frag == PV A-frag
    }

    // ---- O += P · V; V reads LINEAR b64 ----
    const char* vb = smem + cur + kq * 16384 + 8192 + lane * 8;
#pragma unroll
    for (int dt = 0; dt < 16; ++dt) {
      const bf16x4v vf = *(const bf16x4v*)(vb + dt * 512);
      o[0][dt] = mfma_x16(pa[0], vf, o[0][dt]);
      o[1][dt] = mfma_x16(pa[1], vf, o[1][dt]);
    }
  }

  // ---- merge 4 kq partials ----
  float* mlf = (float*)(smem + 133120);  // beyond both buffers: no race
  if (quad == 0) {
#pragma unroll
    for (int qsub = 0; qsub < 2; ++qsub) {
      const int base = ((kq * 2 + qs) * 2 + qsub) * 32;
      mlf[base + l16] = m_[qsub];
      mlf[base + 16 + l16] = l_[qsub];
    }
  }
  __syncthreads();
#pragma unroll
  for (int qsub = 0; qsub < 2; ++qsub) {
    float M = -1e30f, mk[4], lk[4];
#pragma unroll
    for (int k2 = 0; k2 < 4; ++k2) {
      const int base = ((k2 * 2 + qs) * 2 + qsub) * 32;
      mk[k2] = mlf[base + l16];
      lk[k2] = mlf[base + 16 + l16];
      M = fmaxf(M, mk[k2]);
    }
    float L = 0.f;
#pragma unroll
    for (int k2 = 0; k2 < 4; ++k2) L += lk[k2] * fast_exp2(mk[k2] - M);
    const float sg = fast_exp2(m_[qsub] - M) / L;
    float sr[4];
#pragma unroll
    for (int r = 0; r < 4; ++r) sr[r] = __shfl(sg, (quad << 4) + (quad << 2) + r);
#pragma unroll
    for (int dt = 0; dt < 16; ++dt)
#pragma unroll
      for (int r = 0; r < 4; ++r) o[qsub][dt][r] *= sr[r];
  }
  if (kq >= 2) {
#pragma unroll
    for (int qsub = 0; qsub < 2; ++qsub) {
      float* sb = (float*)(smem + ((kq - 2) * 4 + qs * 2 + qsub) * SLOT_SZ);
#pragma unroll
      for (int dt = 0; dt < 16; ++dt)
#pragma unroll
        for (int r = 0; r < 4; ++r)
          sb[(quad * 4 + r) * 260 + dt * 16 + l16] = o[qsub][dt][r];
    }
  }
  __syncthreads();
  if (kq < 2) {
#pragma unroll
    for (int qsub = 0; qsub < 2; ++qsub) {
      const float* sb = (const float*)(smem + (kq * 4 + qs * 2 + qsub) * SLOT_SZ);
#pragma unroll
      for (int dt = 0; dt < 16; ++dt)
#pragma unroll
        for (int r = 0; r < 4; ++r)
          o[qsub][dt][r] += sb[(quad * 4 + r) * 260 + dt * 16 + l16];
    }
  }
  __syncthreads();
  if (kq == 1) {
#pragma unroll
    for (int qsub = 0; qsub < 2; ++qsub) {
      float* sb = (float*)(smem + (qs * 2 + qsub) * SLOT_SZ);
#pragma unroll
      for (int dt = 0; dt < 16; ++dt)
#pragma unroll
        for (int r = 0; r < 4; ++r)
          sb[(quad * 4 + r) * 260 + dt * 16 + l16] = o[qsub][dt][r];
    }
  }
  __syncthreads();
  if (kq == 0) {
#pragma unroll
    for (int qsub = 0; qsub < 2; ++qsub) {
      const float* sb = (const float*)(smem + (qs * 2 + qsub) * SLOT_SZ);
#pragma unroll
      for (int dt = 0; dt < 16; ++dt)
#pragma unroll
        for (int r = 0; r < 4; ++r) {
          const float v = o[qsub][dt][r] + sb[(quad * 4 + r) * 260 + dt * 16 + l16];
          out[(qrow0 + qsub * 16 + quad * 4 + r) * 256 + dt * 16 + l16] = v;
        }
    }
  }
}

extern "C" void kernel_launch(void* const* d_in, const int* in_sizes, int n_in,
                              void* d_out, int out_size, void* d_ws,
                              size_t ws_size, hipStream_t stream) {
  const float* x = (const float*)d_in[0];
  const float* Wq = (const float*)d_in[1];
  const float* bq = (const float*)d_in[2];
  const float* Wk = (const float*)d_in[3];
  const float* bk = (const float*)d_in[4];
  const float* Wv = (const float*)d_in[5];
  const float* bv = (const float*)d_in[6];
  float* out = (float*)d_out;
  char* ws = (char*)d_ws;

  prep_wt<<<768, 256, 0, stream>>>(Wq, Wk, Wv, (bf16*)(ws + WT_OFF));
  proj_qkv<<<768, 256, 0, stream>>>(x, bq, bk, bv, ws);
  flash_attn<<<256, 512, 0, stream>>>(ws, out);
}

// Round 2
// 176.030 us; speedup vs baseline: 1.0113x; 1.0065x over previous
//
#include <hip/hip_runtime.h>

typedef __bf16 bf16;
typedef __bf16 bf16x4v __attribute__((ext_vector_type(4)));
typedef __bf16 bf16x8 __attribute__((ext_vector_type(8)));
typedef float f32x4 __attribute__((ext_vector_type(4)));
typedef short s16x4 __attribute__((ext_vector_type(4)));

#define MFMA_X32(A, B, C) __builtin_amdgcn_mfma_f32_16x16x32_bf16(A, B, C, 0, 0, 0)

#if __has_builtin(__builtin_amdgcn_mfma_f32_16x16x16_bf16)
static __device__ __forceinline__ f32x4 mfma_x16(bf16x4v a, bf16x4v b, f32x4 c) {
  return __builtin_amdgcn_mfma_f32_16x16x16_bf16(a, b, c, 0, 0, 0);
}
#else
static __device__ __forceinline__ f32x4 mfma_x16(bf16x4v a, bf16x4v b, f32x4 c) {
  return __builtin_amdgcn_mfma_f32_16x16x16bf16_1k(
      __builtin_bit_cast(s16x4, a), __builtin_bit_cast(s16x4, b), c, 0, 0, 0);
}
#endif

static __device__ __forceinline__ float fast_exp2(float x) {
  float r;
  asm volatile("v_exp_f32 %0, %1\n\ts_nop 0" : "=v"(r) : "v"(x));
  return r;
}

static __device__ __forceinline__ void gll16(const void* g, void* l) {
  __builtin_amdgcn_global_load_lds(
      (const __attribute__((address_space(1))) void*)g,
      (__attribute__((address_space(3))) void*)l, 16, 0, 0);
}

// ---- workspace byte offsets (UNCHANGED — flash layout contracts intact) ----
#define WT_OFF 0              // Wt bf16 [3][256 n][256 k]          (384 KB)
#define Q_OFF 393216          // Q' bf16 [16384][256] (pre-scaled)   (8 MB)
#define K_OFF 8781824         // Kc bf16 chunk-permuted (see below)  (8 MB)
#define V_OFF 17170432        // Vc bf16 chunk-permuted (see below)  (8 MB)
// Kc: per (b, 16-key chunk) 8KB block; element (key s, dim n) at
//   (n>>5)*512 + ((n>>3)&3)*128 + (s&15)*8 + (n&7)
// Vc: per (b, 16-key chunk) 8KB block; element (key s, dim d=n) at
//   (n>>4)*256 + ((s&15)>>2)*64 + (n&15)*4 + (s&3)
// For a fixed 128-col half ch, a chunk's half is CONTIGUOUS (proj exploits).

// ---------------------------------------------------------------------------
// Kernel 1: W [k][n] fp32 -> Wt bf16 [p][n][k]   (unchanged)
// ---------------------------------------------------------------------------
__global__ __launch_bounds__(256) void prep_wt(const float* __restrict__ Wq,
                                               const float* __restrict__ Wk,
                                               const float* __restrict__ Wv,
                                               bf16* __restrict__ Wt) {
  const int idx = blockIdx.x * 256 + threadIdx.x;
  const int p = idx >> 16;
  const int rem = idx & 65535;  // k*256 + n
  const int k = rem >> 8, n = rem & 255;
  const float* W = (p == 0) ? Wq : ((p == 1) ? Wk : Wv);
  Wt[p * 65536 + n * 256 + k] = (bf16)W[rem];
}

// ---------------------------------------------------------------------------
// Kernel 2: weight-stationary QKV projection (unchanged from R1).
// ---------------------------------------------------------------------------
__global__ __launch_bounds__(256, 3) void proj_qkv(const float* __restrict__ x,
                                                   const float* __restrict__ bq,
                                                   const float* __restrict__ bk,
                                                   const float* __restrict__ bv,
                                                   char* __restrict__ ws0) {
  __shared__ __align__(16) char smem[40960];  // 2 x 16KB swizzled x-tile + 8KB out
  const bf16* Wt = (const bf16*)(ws0 + WT_OFF);
  bf16* Qo = (bf16*)(ws0 + Q_OFF);
  bf16* Ko = (bf16*)(ws0 + K_OFF);
  bf16* Vc = (bf16*)(ws0 + V_OFF);
  const int t = threadIdx.x;
  const int lane = t & 63, w = t >> 6, l16 = lane & 15, quad = lane >> 4;
  const int fam = blockIdx.x % 6;    // consecutive blocks: same rows, all 6
  const int rgroup = blockIdx.x / 6; // families -> x tiles L2/L3-hot across XCDs
  const int p = fam >> 1, ch = fam & 1;
  const float* bias = (p == 0) ? bq : ((p == 1) ? bk : bv);
  const float sc = (p == 0) ? 0.09016844005556021f : 1.0f;  // log2e/16

  // ---- persistent B-frags: wave owns 32 cols (2 x 16), full K=256 ----
  const int nl = w * 32 + l16;  // block-local col, nt adds +16
  bf16x8 bfr[2][8];
#pragma unroll
  for (int nt = 0; nt < 2; ++nt)
#pragma unroll
    for (int kt = 0; kt < 8; ++kt)
      bfr[nt][kt] = *(const bf16x8*)&Wt[p * 65536 + (ch * 128 + nl + nt * 16) * 256 +
                                        kt * 32 + quad * 8];
  float bias2[2];
#pragma unroll
  for (int nt = 0; nt < 2; ++nt) bias2[nt] = bias[ch * 128 + nl + nt * 16];

  const int row0 = rgroup * 128;  // global first row of this block
  char* outL = smem + 32768;

  float4 xr[4][2];  // in-flight x tile (32 rows x 256 fp32 / 256 thr = 128B/thr)
#define STAGE_LOAD(tile)                                                        \
  {                                                                             \
    const float* xp = x + (row0 + (tile) * 32) * 256;                           \
    _Pragma("unroll") for (int i = 0; i < 4; ++i) {                             \
      const int u2 = i * 256 + t, row = u2 >> 5, col8 = (u2 & 31) * 8;          \
      xr[i][0] = *(const float4*)&xp[row * 256 + col8];                         \
      xr[i][1] = *(const float4*)&xp[row * 256 + col8 + 4];                     \
    }                                                                           \
  }
#define STAGE_WRITE(buf)                                                        \
  {                                                                             \
    _Pragma("unroll") for (int i = 0; i < 4; ++i) {                             \
      const int u2 = i * 256 + t, row = u2 >> 5, col8 = (u2 & 31) * 8;          \
      const float* f0 = (const float*)&xr[i][0];                                \
      const float* f1 = (const float*)&xr[i][1];                                \
      bf16x8 h;                                                                 \
      _Pragma("unroll") for (int j = 0; j < 4; ++j) {                           \
        h[j] = (bf16)f0[j];                                                     \
        h[4 + j] = (bf16)f1[j];                                                 \
      }                                                                         \
      *(bf16x8*)&smem[(buf) * 16384 + row * 512 +                               \
                      ((col8 * 2) ^ ((row & 7) << 4))] = h;                     \
    }                                                                           \
  }

  STAGE_LOAD(0);
  STAGE_WRITE(0);
  __syncthreads();

  int cur = 0;
  for (int tt = 0; tt < 4; ++tt) {
    if (tt < 3) STAGE_LOAD(tt + 1);  // issue early; consumed after next barrier

    // ---- 32 MFMAs from swizzled LDS A-frags + register B-frags ----
    f32x4 acc[2][2];
#pragma unroll
    for (int rs = 0; rs < 2; ++rs)
#pragma unroll
      for (int nt = 0; nt < 2; ++nt) acc[rs][nt] = f32x4{0.f, 0.f, 0.f, 0.f};
    const char* xb = smem + cur * 16384;
#pragma unroll
    for (int rs = 0; rs < 2; ++rs) {
      const int row = rs * 16 + l16;
#pragma unroll
      for (int kt = 0; kt < 8; ++kt) {
        const bf16x8 a = *(const bf16x8*)(xb + row * 512 +
                                          ((kt * 64 + quad * 16) ^ ((l16 & 7) << 4)));
        acc[rs][0] = MFMA_X32(a, bfr[0][kt], acc[rs][0]);
        acc[rs][1] = MFMA_X32(a, bfr[1][kt], acc[rs][1]);
      }
    }
    __syncthreads();  // prev tile's coop-write reads of outL complete

    // ---- scatter acc into outL in the flash permutation ----
#pragma unroll
    for (int rs = 0; rs < 2; ++rs)
#pragma unroll
      for (int nt = 0; nt < 2; ++nt)
#pragma unroll
        for (int r = 0; r < 4; ++r) {
          const int sl = rs * 16 + quad * 4 + r;  // C/D: row = quad*4+r
          const int nn = nl + nt * 16;            // block-local col 0..127
          const bf16 hv = (bf16)((acc[rs][nt][r] + bias2[nt]) * sc);
          int pos;
          if (p == 0)
            pos = sl * 128 + nn;
          else if (p == 1)
            pos = (sl >> 4) * 2048 + (nn >> 5) * 512 + ((nn >> 3) & 3) * 128 +
                  (sl & 15) * 8 + (nn & 7);
          else
            pos = (sl >> 4) * 2048 + (nn >> 4) * 256 + ((sl & 15) >> 2) * 64 +
                  (nn & 15) * 4 + (sl & 3);
          *(bf16*)(outL + pos * 2) = hv;
        }
    if (tt < 3) STAGE_WRITE(cur ^ 1);
    __syncthreads();  // scatter + next x-tile visible to all waves

    // ---- coalesced 32B/thread write of the 8KB out tile ----
    const int rowg = row0 + tt * 32;
    if (p == 0) {
      const int row = t >> 3, cb = (t & 7) * 32;
      const float4 v0 = *(const float4*)(outL + row * 256 + cb);
      const float4 v1 = *(const float4*)(outL + row * 256 + cb + 16);
      char* dst = (char*)Qo + (rowg + row) * 512 + ch * 256 + cb;
      *(float4*)dst = v0;
      *(float4*)(dst + 16) = v1;
    } else {
      const int b2 = rowg >> 11, s0 = rowg & 2047;
      bf16* O = (p == 1) ? Ko : Vc;
      char* dst = (char*)O + b2 * 1048576 + ((s0 >> 4) + (t >> 7)) * 8192 +
                  ch * 4096 + (t & 127) * 32;
      const float4 v0 = *(const float4*)(outL + t * 32);
      const float4 v1 = *(const float4*)(outL + t * 32 + 16);
      *(float4*)dst = v0;
      *(float4*)(dst + 16) = v1;
    }
    cur ^= 1;
  }
#undef STAGE_LOAD
#undef STAGE_WRITE
}

// ---------------------------------------------------------------------------
// Kernel 3 (RESTRUCTURED): flash attention at 4 waves/SIMD.
// 1024 threads = 16 waves = (qw in 0..3) x (kq in 0..3); wave = 16 Q rows x
// 512 keys. Per-wave state halves vs R1 (o[16]=64 VGPR, qf[8]=32 VGPR) ->
// fits 128-reg bin -> 16 waves/CU (was 8). Same 64KB double-buffered GLL
// staging (4 GLL/wave/iter), same 16-key chunks, same kq=4 merge tree:
// per-(row,kq) arithmetic is bit-identical to R1. s_setprio(1) around MFMA
// clusters (T5, +4-7% attn measured).
// ---------------------------------------------------------------------------
#define BUF_SZ 65536   // half: 4 kq * (K 8KB + V 8KB), no pads
#define SLOT_SZ 16640  // merge slot: 16 rows * 260 floats

__global__ __launch_bounds__(1024, 4) void flash_attn(const char* __restrict__ ws0,
                                                      float* __restrict__ out) {
  __shared__ __align__(1024) char smem[135168];  // 2*BUF_SZ + merge scratch
  const bf16* Qp = (const bf16*)(ws0 + Q_OFF);
  const int t = threadIdx.x;
  const int lane = t & 63, w = t >> 6;
  const int l16 = lane & 15, quad = lane >> 4;
  const int qw = w & 3, kq = w >> 2;
  const int b = blockIdx.x & 7;  // batch == XCD round-robin: K/V L2-resident
  const int qt = blockIdx.x >> 3;
  const int qrow0 = b * 2048 + qt * 64;  // block owns 64 rows; wave owns 16

  bf16x8 qf[8];
#pragma unroll
  for (int kt = 0; kt < 8; ++kt)
    qf[kt] = *(const bf16x8*)&Qp[(qrow0 + qw * 16 + l16) * 256 + kt * 32 + quad * 8];

  f32x4 o[16];
#pragma unroll
  for (int dt = 0; dt < 16; ++dt) o[dt] = f32x4{0.f, 0.f, 0.f, 0.f};
  float m_ = -1e30f, l_ = 0.f;

  // staging assignment: 4 GLL units (1 KB each) per wave per iter (64 total)
  unsigned goff[4], loff[4];
#pragma unroll
  for (int i = 0; i < 4; ++i) {
    const int u = w * 4 + i;
    const int kq2 = (u & 31) >> 3, e = u & 7;
    goff[i] = (u < 32 ? (unsigned)K_OFF : (unsigned)V_OFF) + b * 1048576u +
              kq2 * 262144u + e * 1024u + lane * 16u;
    loff[i] = kq2 * 16384u + (u < 32 ? 0u : 8192u) + e * 1024u;
  }
#pragma unroll
  for (int i = 0; i < 4; ++i) gll16(ws0 + goff[i], smem + loff[i]);

  for (int it = 0; it < 32; ++it) {
    __syncthreads();  // chunk `it` resident; prev-iter reads of `nxt` done
    const unsigned cur = (unsigned)(it & 1) * BUF_SZ;
    if (it + 1 < 32) {
      const unsigned nxt = (unsigned)((it + 1) & 1) * BUF_SZ;
      const unsigned gadd = (unsigned)(it + 1) * 8192u;
#pragma unroll
      for (int i = 0; i < 4; ++i) gll16(ws0 + goff[i] + gadd, smem + nxt + loff[i]);
    }

    // ---- Sᵀ = K_chunk · Q'ᵀ (16 keys x 16 q); K reads LINEAR b128 ----
    const char* kb = smem + cur + kq * 16384 + lane * 16;
    f32x4 s0 = f32x4{0.f, 0.f, 0.f, 0.f};
    __builtin_amdgcn_s_setprio(1);
#pragma unroll
    for (int kt = 0; kt < 8; ++kt) {
      const bf16x8 kf = *(const bf16x8*)(kb + kt * 1024);
      s0 = MFMA_X32(kf, qf[kt], s0);
    }
    __builtin_amdgcn_s_setprio(0);

    // ---- online softmax (log2 domain; q = l16, key = quad*4+r) ----
    float cm = fmaxf(fmaxf(s0[0], s0[1]), fmaxf(s0[2], s0[3]));
    cm = fmaxf(cm, __shfl_xor(cm, 16));
    cm = fmaxf(cm, __shfl_xor(cm, 32));
    const float mold = m_;
    const float mnew = fmaxf(mold, cm);
    bf16x4v pa;
    float ps = 0.f;
#pragma unroll
    for (int r = 0; r < 4; ++r) {
      const float e = fast_exp2(s0[r] - mnew);
      const bf16 pb = (bf16)e;
      pa[r] = pb;
      ps += (float)pb;  // sum ROUNDED p for O/l consistency
    }
    ps += __shfl_xor(ps, 16);
    ps += __shfl_xor(ps, 32);
    if (__any(mnew > mold)) {
      const float al = fast_exp2(mold - mnew);
      m_ = mnew;
      l_ = l_ * al + ps;
      float ar[4];
#pragma unroll
      for (int r = 0; r < 4; ++r)
        ar[r] = __shfl(al, (quad << 4) + (quad << 2) + r);
#pragma unroll
      for (int dt = 0; dt < 16; ++dt)
#pragma unroll
        for (int r = 0; r < 4; ++r) o[dt][r] *= ar[r];
    } else {
      l_ += ps;
    }

    // ---- O += P · V; V reads LINEAR b64 ----
    const char* vb = smem + cur + kq * 16384 + 8192 + lane * 8;
    __builtin_amdgcn_s_setprio(1);
#pragma unroll
    for (int dt = 0; dt < 16; ++dt) {
      const bf16x4v vf = *(const bf16x4v*)(vb + dt * 512);
      o[dt] = mfma_x16(pa, vf, o[dt]);
    }
    __builtin_amdgcn_s_setprio(0);
  }

  // ---- merge 4 kq partials (per qw) ----
  float* mlf = (float*)(smem + 133120);  // beyond both buffers: no race
  if (quad == 0) {
    const int base = (kq * 4 + qw) * 32;
    mlf[base + l16] = m_;
    mlf[base + 16 + l16] = l_;
  }
  __syncthreads();  // also: all last-iter LDS reads done before slot overwrite
  {
    float M = -1e30f, mk[4], lk[4];
#pragma unroll
    for (int k2 = 0; k2 < 4; ++k2) {
      const int base = (k2 * 4 + qw) * 32;
      mk[k2] = mlf[base + l16];
      lk[k2] = mlf[base + 16 + l16];
      M = fmaxf(M, mk[k2]);
    }
    float L = 0.f;
#pragma unroll
    for (int k2 = 0; k2 < 4; ++k2) L += lk[k2] * fast_exp2(mk[k2] - M);
    const float sg = fast_exp2(m_ - M) / L;
    float sr[4];
#pragma unroll
    for (int r = 0; r < 4; ++r) sr[r] = __shfl(sg, (quad << 4) + (quad << 2) + r);
#pragma unroll
    for (int dt = 0; dt < 16; ++dt)
#pragma unroll
      for (int r = 0; r < 4; ++r) o[dt][r] *= sr[r];
  }
  if (kq >= 2) {
    float* sb = (float*)(smem + ((kq - 2) * 4 + qw) * SLOT_SZ);
#pragma unroll
    for (int dt = 0; dt < 16; ++dt)
#pragma unroll
      for (int r = 0; r < 4; ++r)
        sb[(quad * 4 + r) * 260 + dt * 16 + l16] = o[dt][r];
  }
  __syncthreads();
  if (kq < 2) {
    const float* sb = (const float*)(smem + (kq * 4 + qw) * SLOT_SZ);
#pragma unroll
    for (int dt = 0; dt < 16; ++dt)
#pragma unroll
      for (int r = 0; r < 4; ++r)
        o[dt][r] += sb[(quad * 4 + r) * 260 + dt * 16 + l16];
  }
  __syncthreads();
  if (kq == 1) {
    float* sb = (float*)(smem + qw * SLOT_SZ);
#pragma unroll
    for (int dt = 0; dt < 16; ++dt)
#pragma unroll
      for (int r = 0; r < 4; ++r)
        sb[(quad * 4 + r) * 260 + dt * 16 + l16] = o[dt][r];
  }
  __syncthreads();
  if (kq == 0) {
    const float* sb = (const float*)(smem + qw * SLOT_SZ);
#pragma unroll
    for (int dt = 0; dt < 16; ++dt)
#pragma unroll
      for (int r = 0; r < 4; ++r) {
        const float v = o[dt][r] + sb[(quad * 4 + r) * 260 + dt * 16 + l16];
        out[(qrow0 + qw * 16 + quad * 4 + r) * 256 + dt * 16 + l16] = v;
      }
  }
}

extern "C" void kernel_launch(void* const* d_in, const int* in_sizes, int n_in,
                              void* d_out, int out_size, void* d_ws,
                              size_t ws_size, hipStream_t stream) {
  const float* x = (const float*)d_in[0];
  const float* Wq = (const float*)d_in[1];
  const float* bq = (const float*)d_in[2];
  const float* Wk = (const float*)d_in[3];
  const float* bk = (const float*)d_in[4];
  const float* Wv = (const float*)d_in[5];
  const float* bv = (const float*)d_in[6];
  float* out = (float*)d_out;
  char* ws = (char*)d_ws;

  prep_wt<<<768, 256, 0, stream>>>(Wq, Wk, Wv, (bf16*)(ws + WT_OFF));
  proj_qkv<<<768, 256, 0, stream>>>(x, bq, bk, bv, ws);
  flash_attn<<<256, 1024, 0, stream>>>(ws, out);
}